// Round 4
// baseline (904.139 us; speedup 1.0000x reference)
//
#include <hip/hip_runtime.h>
#include <hip/hip_bf16.h>

typedef __bf16 bf16x8 __attribute__((ext_vector_type(8)));
typedef __bf16 bf16x4 __attribute__((ext_vector_type(4)));
typedef __bf16 bf16x2 __attribute__((ext_vector_type(2)));
typedef float  f32x4  __attribute__((ext_vector_type(4)));
typedef float  f32x16 __attribute__((ext_vector_type(16)));

#define DIM   1024
#define BSZ   4
#define LSEQ  8192
#define M_TOT (BSZ*LSEQ)      /* 32768 rows */
#define CHUNKS 64
#define CLEN  (LSEQ/CHUNKS)   /* 128 */

__device__ __forceinline__ float sigmoid_f(float z){ return 1.0f/(1.0f + __expf(-z)); }
__device__ __forceinline__ float tanh_f(float z){ return 1.0f - 2.0f/(__expf(2.0f*z) + 1.0f); }

// ---------------- prepass: x (fp32) -> x_hi, x_lo (bf16 split) ----------------
__global__ __launch_bounds__(256) void k_convert_x(const float* __restrict__ x,
                                                   __bf16* __restrict__ xh,
                                                   __bf16* __restrict__ xl){
    int i = (blockIdx.x*256 + threadIdx.x)*4;
    float4 v = *(const float4*)(x + i);
    float vv[4] = {v.x, v.y, v.z, v.w};
    bf16x4 h, l;
#pragma unroll
    for(int j=0;j<4;j++){
        __bf16 hj = (__bf16)vv[j];
        h[j] = hj;
        l[j] = (__bf16)(vv[j] - (float)hj);
    }
    *(bf16x4*)(xh + i) = h;
    *(bf16x4*)(xl + i) = l;
}

// ---------------- prepass: W (fp32, [k][n]) -> WT (bf16, [n][k]), 4 gates ----------------
__global__ __launch_bounds__(256) void k_convert_w(const float* __restrict__ W0,
                                                   const float* __restrict__ W1,
                                                   const float* __restrict__ W2,
                                                   const float* __restrict__ W3,
                                                   __bf16* __restrict__ WT){
    __shared__ float t[32][33];
    int tx = threadIdx.x, ty = threadIdx.y;          // block (32,8)
    int n0 = blockIdx.x*32, k0 = blockIdx.y*32;
    int g = blockIdx.z;
    const float* W = (g==0)?W0:(g==1)?W1:(g==2)?W2:W3;
    __bf16* wt = WT + (size_t)g*DIM*DIM;
#pragma unroll
    for(int j=0;j<4;j++)
        t[ty + j*8][tx] = W[(size_t)(k0 + ty + j*8)*DIM + n0 + tx];
    __syncthreads();
#pragma unroll
    for(int j=0;j<4;j++)
        wt[(size_t)(n0 + ty + j*8)*DIM + k0 + tx] = (__bf16)t[tx][ty + j*8];
}

// ---------------- unified 4-gate GEMM: 256M x 64N(x4 gates), 32x32x16 MFMA ----------------
// 512 threads = 8 waves (4 M-quarters x 2 N-halves). BK=32.
// LDS: 3 buffers x 48 KiB = 144 KiB (1 block/CU, 8 waves/CU).
//   buffer = [A_hi 16K][A_lo 16K][B 16K]; each region 256 rows x 64 B.
// Row swizzle (FIXED vs R3): 16B slot s of row r holds global k-seg s ^ ((r>>1)&3).
//   Within an 8-lane ds_read_b128 phase (rows r..r+7, 64B stride), rows {r,r+2,r+4,r+6}
//   take 4 distinct slots -> all 32 banks covered once -> conflict-free (R0/R1-verified form).
//   R3's (r&3) variant gave lanes l and l+4 the same bank quad -> 1.0e8 conflicts.
// Pipeline: depth-2 counted vmcnt. Per K-step: vmcnt(6); s_barrier; STAGE(kt+2); reads+MFMA.
__global__ __launch_bounds__(512) void k_gemm(
        const __bf16* __restrict__ xh, const __bf16* __restrict__ xl,
        const __bf16* __restrict__ WT,            // [4][DIM][DIM], n-major
        const float* __restrict__ b0, const float* __restrict__ b1,
        const float* __restrict__ b2, const float* __restrict__ b3,
        __bf16* __restrict__ F, __bf16* __restrict__ INP, __bf16* __restrict__ G)
{
    __shared__ __bf16 smem[3*24576];   // 144 KiB
    const int tid = threadIdx.x;
    const int nb = blockIdx.x, mb = blockIdx.y;

    const __bf16* ah = xh + (size_t)mb*256*DIM;
    const __bf16* al = xl + (size_t)mb*256*DIM;

    const int lane = tid & 63, wv = tid >> 6;
    const int wm = wv & 3, wn = wv >> 2;          // 4 M-quarters(64 rows) x 2 N-halves(32 cols)
    const int l31 = lane & 31, hi = lane >> 5;

    f32x16 acc[4][2];
#pragma unroll
    for(int g=0;g<4;g++)
#pragma unroll
        for(int mt=0;mt<2;mt++)
#pragma unroll
            for(int r=0;r<16;r++) acc[g][mt][r] = 0.f;

    // ---- staging precompute: thread t stages 16B at region offset t*16.
    // LDS offset o: row r = o>>6, slot = (o>>4)&3; holds global k-seg slot^((r>>1)&3).
    // r = tid>>2 -> (r>>1)&3 = (tid>>3)&3.
    const int rr   = tid >> 2;                                  // 0..127
    const int sseg = ((tid & 3) ^ ((tid >> 3) & 3)) * 8;        // element offset in BK=32
    const __bf16* sa_h0 = ah + (size_t)(rr      )*DIM + sseg;
    const __bf16* sa_h1 = ah + (size_t)(rr + 128)*DIM + sseg;
    const __bf16* sa_l0 = al + (size_t)(rr      )*DIM + sseg;
    const __bf16* sa_l1 = al + (size_t)(rr + 128)*DIM + sseg;
    const __bf16* sb_0  = WT + (size_t)(rr>>6)*DIM*DIM
                             + (size_t)(nb*64 + (rr&63))*DIM + sseg;        // gates 0,1
    const __bf16* sb_1  = WT + (size_t)((rr+128)>>6)*DIM*DIM
                             + (size_t)(nb*64 + (rr&63))*DIM + sseg;        // gates 2,3
    char* lds_c = (char*)smem;

#define GLDS(p, dst) __builtin_amdgcn_global_load_lds( \
        (const __attribute__((address_space(1))) void*)(p), \
        (__attribute__((address_space(3))) void*)(dst), 16, 0, 0)

#define STAGE(BB, K0) do{ \
        char* _b = (BB); \
        GLDS(sa_h0 + (K0), _b +         tid*16); \
        GLDS(sa_h1 + (K0), _b +  8192 + tid*16); \
        GLDS(sa_l0 + (K0), _b + 16384 + tid*16); \
        GLDS(sa_l1 + (K0), _b + 24576 + tid*16); \
        GLDS(sb_0  + (K0), _b + 32768 + tid*16); \
        GLDS(sb_1  + (K0), _b + 40960 + tid*16); \
    }while(0)

    // ---- fragment read offsets. A row = wm*64 + mt*32 + l31; B row = g*64 + wn*32 + l31.
    // (row>>1)&3 == (l31>>1)&3 for all (offsets are multiples of 32) -> slot constant per lane.
    const int soff0 = (((0*2 + hi) ^ ((l31 >> 1) & 3)))*16;   // ks=0
    const int soff1 = (((1*2 + hi) ^ ((l31 >> 1) & 3)))*16;   // ks=1
    const int rowAb = (wm*64 + l31)*64;                // byte base of A row (mt=0)
    const int rowBb = (wn*32 + l31)*64;                // byte base of B row (g=0)

    STAGE(lds_c,         0);
    STAGE(lds_c + 49152, 32);
    int cb = 0;

#pragma unroll 1
    for(int kt=0; kt<DIM/32; ++kt){
        if(kt < DIM/32 - 1) asm volatile("s_waitcnt vmcnt(6)" ::: "memory");
        else                asm volatile("s_waitcnt vmcnt(0)" ::: "memory");
        __builtin_amdgcn_s_barrier();
        asm volatile("" ::: "memory");

        if(kt < DIM/32 - 2){
            int fb = cb + 2; if(fb >= 3) fb -= 3;
            STAGE(lds_c + fb*49152, (kt+2)*32);
        }
        const char* cbp = lds_c + cb*49152;

#pragma unroll
        for(int ks=0; ks<2; ++ks){
            const int so = ks ? soff1 : soff0;
            bf16x8 a0h = *(const bf16x8*)(cbp +         rowAb        + so);
            bf16x8 a1h = *(const bf16x8*)(cbp +         rowAb + 2048 + so);   // mt=1: +32 rows
            bf16x8 a0l = *(const bf16x8*)(cbp + 16384 + rowAb        + so);
            bf16x8 a1l = *(const bf16x8*)(cbp + 16384 + rowAb + 2048 + so);
            bf16x8 bg0 = *(const bf16x8*)(cbp + 32768 + rowBb        + so);
            bf16x8 bg1 = *(const bf16x8*)(cbp + 32768 + rowBb + 4096 + so);
            bf16x8 bg2 = *(const bf16x8*)(cbp + 32768 + rowBb + 8192 + so);
            bf16x8 bg3 = *(const bf16x8*)(cbp + 32768 + rowBb + 12288 + so);
            // 8 independent hi-MFMAs, then 8 lo-MFMAs (each depends on its hi, 8 apart)
            acc[0][0] = __builtin_amdgcn_mfma_f32_32x32x16_bf16(a0h, bg0, acc[0][0], 0,0,0);
            acc[1][0] = __builtin_amdgcn_mfma_f32_32x32x16_bf16(a0h, bg1, acc[1][0], 0,0,0);
            acc[2][0] = __builtin_amdgcn_mfma_f32_32x32x16_bf16(a0h, bg2, acc[2][0], 0,0,0);
            acc[3][0] = __builtin_amdgcn_mfma_f32_32x32x16_bf16(a0h, bg3, acc[3][0], 0,0,0);
            acc[0][1] = __builtin_amdgcn_mfma_f32_32x32x16_bf16(a1h, bg0, acc[0][1], 0,0,0);
            acc[1][1] = __builtin_amdgcn_mfma_f32_32x32x16_bf16(a1h, bg1, acc[1][1], 0,0,0);
            acc[2][1] = __builtin_amdgcn_mfma_f32_32x32x16_bf16(a1h, bg2, acc[2][1], 0,0,0);
            acc[3][1] = __builtin_amdgcn_mfma_f32_32x32x16_bf16(a1h, bg3, acc[3][1], 0,0,0);
            acc[0][0] = __builtin_amdgcn_mfma_f32_32x32x16_bf16(a0l, bg0, acc[0][0], 0,0,0);
            acc[1][0] = __builtin_amdgcn_mfma_f32_32x32x16_bf16(a0l, bg1, acc[1][0], 0,0,0);
            acc[2][0] = __builtin_amdgcn_mfma_f32_32x32x16_bf16(a0l, bg2, acc[2][0], 0,0,0);
            acc[3][0] = __builtin_amdgcn_mfma_f32_32x32x16_bf16(a0l, bg3, acc[3][0], 0,0,0);
            acc[0][1] = __builtin_amdgcn_mfma_f32_32x32x16_bf16(a1l, bg0, acc[0][1], 0,0,0);
            acc[1][1] = __builtin_amdgcn_mfma_f32_32x32x16_bf16(a1l, bg1, acc[1][1], 0,0,0);
            acc[2][1] = __builtin_amdgcn_mfma_f32_32x32x16_bf16(a1l, bg2, acc[2][1], 0,0,0);
            acc[3][1] = __builtin_amdgcn_mfma_f32_32x32x16_bf16(a1l, bg3, acc[3][1], 0,0,0);
        }
        if(++cb == 3) cb = 0;
    }
#undef STAGE
#undef GLDS

    // epilogue: C/D frag (32x32): col = lane&31, row = (r&3) + 8*(r>>2) + 4*hi
    const int col = nb*64 + wn*32 + l31;
    const float bvf = b0[col], bvi = b1[col], bvg = b2[col], bvo = b3[col];
#pragma unroll
    for(int mt=0; mt<2; ++mt){
#pragma unroll
        for(int r=0; r<16; ++r){
            int m = mb*256 + wm*64 + mt*32 + (r&3) + 8*(r>>2) + 4*hi;
            size_t o = (size_t)m*DIM + col;
            F[o]   = (__bf16)sigmoid_f(acc[0][mt][r] + bvf);
            float it = tanh_f   (acc[1][mt][r] + bvi);
            float ig = sigmoid_f(acc[2][mt][r] + bvg);
            INP[o] = (__bf16)(it*ig);
            G[o]   = (__bf16)sigmoid_f(acc[3][mt][r] + bvo);
        }
    }
}

// ---------------- scan pass 1: per-chunk (P = prod f, H = local scan from 0) ----------------
__global__ __launch_bounds__(256) void k_scan1(const __bf16* __restrict__ F, const __bf16* __restrict__ INP,
                                               float* __restrict__ P, float* __restrict__ Hc){
    int c = blockIdx.x, dblk = blockIdx.y, b = blockIdx.z;
    int d = (dblk*256 + threadIdx.x)*2;
    size_t base = ((size_t)(b*LSEQ + c*CLEN))*DIM + d;
    float p0=1.f,p1=1.f,h0=0.f,h1=0.f;
#pragma unroll 4
    for(int t=0;t<CLEN;t++){
        bf16x2 fv = *(const bf16x2*)(F   + base + (size_t)t*DIM);
        bf16x2 iv = *(const bf16x2*)(INP + base + (size_t)t*DIM);
        h0 = (float)fv[0]*h0 + (float)iv[0];
        h1 = (float)fv[1]*h1 + (float)iv[1];
        p0 *= (float)fv[0];
        p1 *= (float)fv[1];
    }
    int bd = b*DIM + d;
    *(float2*)(P  + c*(BSZ*DIM) + bd) = make_float2(p0,p1);
    *(float2*)(Hc + c*(BSZ*DIM) + bd) = make_float2(h0,h1);
}

// ---------------- scan pass 2: chunk-level scan, seeded with last_hidden_init ----------------
__global__ __launch_bounds__(256) void k_scan2(const float* __restrict__ P, const float* __restrict__ Hc,
                                               const float* __restrict__ lh, float* __restrict__ Hin){
    int bd = blockIdx.x*256 + threadIdx.x;   // 0..4095
    int d = bd & (DIM-1);
    float h = lh[d];
#pragma unroll
    for(int c=0;c<CHUNKS;c++){
        Hin[c*(BSZ*DIM) + bd] = h;
        h = P[c*(BSZ*DIM) + bd]*h + Hc[c*(BSZ*DIM) + bd];
    }
}

// ---------------- scan pass 3: replay chunks, fuse y = tanh(h)*G ----------------
__global__ __launch_bounds__(256) void k_scan3(const __bf16* __restrict__ F, const __bf16* __restrict__ INP,
                                               const __bf16* __restrict__ G, const float* __restrict__ Hin,
                                               float* __restrict__ Y){
    int c = blockIdx.x, dblk = blockIdx.y, b = blockIdx.z;
    int d = (dblk*256 + threadIdx.x)*2;
    int bd = b*DIM + d;
    size_t base = ((size_t)(b*LSEQ + c*CLEN))*DIM + d;
    float2 hv = *(const float2*)(Hin + c*(BSZ*DIM) + bd);
    float h0 = hv.x, h1 = hv.y;
#pragma unroll 4
    for(int t=0;t<CLEN;t++){
        size_t o = base + (size_t)t*DIM;
        bf16x2 fv = *(const bf16x2*)(F + o);
        bf16x2 iv = *(const bf16x2*)(INP + o);
        bf16x2 gv = *(const bf16x2*)(G + o);
        h0 = (float)fv[0]*h0 + (float)iv[0];
        h1 = (float)fv[1]*h1 + (float)iv[1];
        *(float2*)(Y + o) = make_float2(tanh_f(h0)*(float)gv[0], tanh_f(h1)*(float)gv[1]);
    }
}

extern "C" void kernel_launch(void* const* d_in, const int* in_sizes, int n_in,
                              void* d_out, int out_size, void* d_ws, size_t ws_size,
                              hipStream_t stream){
    const float* x  = (const float*)d_in[0];
    const float* W[4]    = {(const float*)d_in[1], (const float*)d_in[3],
                            (const float*)d_in[5], (const float*)d_in[7]};
    const float* bias[4] = {(const float*)d_in[2], (const float*)d_in[4],
                            (const float*)d_in[6], (const float*)d_in[8]};
    const float* lh = (const float*)d_in[9];
    float* Y = (float*)d_out;

    char* ws = (char*)d_ws;
    __bf16* xh = (__bf16*)(ws);                         //  64 MiB
    __bf16* xl = (__bf16*)(ws + ((size_t) 64<<20));     //  64 MiB
    __bf16* WT = (__bf16*)(ws + ((size_t)128<<20));     //   8 MiB
    __bf16* F  = (__bf16*)(ws + ((size_t)136<<20));     //  64 MiB
    __bf16* INP= (__bf16*)(ws + ((size_t)200<<20));     //  64 MiB
    __bf16* G  = (__bf16*)(ws + ((size_t)264<<20));     //  64 MiB
    float*  P  = (float*) (ws + ((size_t)328<<20));     //   1 MiB
    float*  Hc = (float*) (ws + ((size_t)329<<20));     //   1 MiB
    float*  Hin= (float*) (ws + ((size_t)330<<20));     //   1 MiB  (total 331 MiB)

    hipLaunchKernelGGL(k_convert_x, dim3(M_TOT*DIM/(4*256)), dim3(256), 0, stream, x, xh, xl);
    hipLaunchKernelGGL(k_convert_w, dim3(32,32,4), dim3(32,8), 0, stream,
                       W[0], W[1], W[2], W[3], WT);
    hipLaunchKernelGGL(k_gemm, dim3(16, M_TOT/256), dim3(512), 0, stream,
                       xh, xl, WT, bias[0], bias[1], bias[2], bias[3], F, INP, G);
    hipLaunchKernelGGL(k_scan1, dim3(CHUNKS, DIM/512, BSZ), dim3(256), 0, stream, F, INP, P, Hc);
    hipLaunchKernelGGL(k_scan2, dim3(BSZ*DIM/256), dim3(256), 0, stream, P, Hc, lh, Hin);
    hipLaunchKernelGGL(k_scan3, dim3(CHUNKS, DIM/512, BSZ), dim3(256), 0, stream, F, INP, G, Hin, Y);
}

// Round 5
// 812.494 us; speedup vs baseline: 1.1128x; 1.1128x over previous
//
#include <hip/hip_runtime.h>
#include <hip/hip_bf16.h>

typedef __bf16 bf16x8 __attribute__((ext_vector_type(8)));
typedef __bf16 bf16x4 __attribute__((ext_vector_type(4)));
typedef __bf16 bf16x2 __attribute__((ext_vector_type(2)));
typedef float  f32x4  __attribute__((ext_vector_type(4)));

#define DIM   1024
#define BSZ   4
#define LSEQ  8192
#define M_TOT (BSZ*LSEQ)      /* 32768 rows */
#define CHUNKS 64
#define CLEN  (LSEQ/CHUNKS)   /* 128 */

__device__ __forceinline__ float sigmoid_f(float z){ return 1.0f/(1.0f + __expf(-z)); }
__device__ __forceinline__ float tanh_f(float z){ return 1.0f - 2.0f/(__expf(2.0f*z) + 1.0f); }

// ---------------- prepass: x (fp32) -> x_hi, x_lo (bf16 split) ----------------
__global__ __launch_bounds__(256) void k_convert_x(const float* __restrict__ x,
                                                   __bf16* __restrict__ xh,
                                                   __bf16* __restrict__ xl){
    int i = (blockIdx.x*256 + threadIdx.x)*4;
    float4 v = *(const float4*)(x + i);
    float vv[4] = {v.x, v.y, v.z, v.w};
    bf16x4 h, l;
#pragma unroll
    for(int j=0;j<4;j++){
        __bf16 hj = (__bf16)vv[j];
        h[j] = hj;
        l[j] = (__bf16)(vv[j] - (float)hj);
    }
    *(bf16x4*)(xh + i) = h;
    *(bf16x4*)(xl + i) = l;
}

// ---------------- prepass: W (fp32, [k][n]) -> WT (bf16, [n][k]), 4 gates ----------------
__global__ __launch_bounds__(256) void k_convert_w(const float* __restrict__ W0,
                                                   const float* __restrict__ W1,
                                                   const float* __restrict__ W2,
                                                   const float* __restrict__ W3,
                                                   __bf16* __restrict__ WT){
    __shared__ float t[32][33];
    int tx = threadIdx.x, ty = threadIdx.y;          // block (32,8)
    int n0 = blockIdx.x*32, k0 = blockIdx.y*32;
    int g = blockIdx.z;
    const float* W = (g==0)?W0:(g==1)?W1:(g==2)?W2:W3;
    __bf16* wt = WT + (size_t)g*DIM*DIM;
#pragma unroll
    for(int j=0;j<4;j++)
        t[ty + j*8][tx] = W[(size_t)(k0 + ty + j*8)*DIM + n0 + tx];
    __syncthreads();
#pragma unroll
    for(int j=0;j<4;j++)
        wt[(size_t)(n0 + ty + j*8)*DIM + k0 + tx] = (__bf16)t[tx][ty + j*8];
}

// ---------------- unified 4-gate GEMM (R1 geometry + counted-vmcnt barriers) ----------------
// Block computes 128(M) x 64(N) for ALL 4 gates. A (hi+lo) staged once per K-step.
// LDS: 2 buffers x 32 KiB (8 regions x 4 KiB each): [0,1]=A_hi rows 0-63/64-127,
// [2,3]=A_lo, [4..7]=B gate 0..3. 64 KiB total -> 2 blocks/CU.
// XOR swizzle (R1-verified, 0 conflicts): element (row r, k-seg q) at r*64 + (q ^ ((r>>1)&3))*16.
//   Conflict-free under BOTH consecutive-8 and {l,l+32} SIMD-half phase groupings
//   (quad = lane>>4 differs by 2 between half-waves -> distinct bank quads).
// Pipeline (NEW vs R1): raw s_barrier pair + counted vmcnt, no per-iter vmcnt(0) drain:
//   iter kt: STAGE(kt+1) ; vmcnt(8) [retires STAGE(kt)] ; s_barrier(B) ; reads+MFMA ; s_barrier(A)
// Barrier A (end of iter) makes prior reads retire-visible -> WAR-safe for next STAGE.
// Each wave's own vmcnt(8) retires its STAGE(kt) LDS-writes BEFORE barrier B publishes them.
__global__ __launch_bounds__(256,2) void k_gemm(
        const __bf16* __restrict__ xh, const __bf16* __restrict__ xl,
        const __bf16* __restrict__ WT,            // [4][DIM][DIM], n-major
        const float* __restrict__ b0, const float* __restrict__ b1,
        const float* __restrict__ b2, const float* __restrict__ b3,
        __bf16* __restrict__ F, __bf16* __restrict__ INP, __bf16* __restrict__ G)
{
    __shared__ __bf16 smem[2*8*2048];   // 64 KiB (2 buffers x 32 KiB)
    const int tid = threadIdx.x;
    const int nb = blockIdx.x, mb = blockIdx.y;

    const __bf16* ah = xh + (size_t)mb*128*DIM;
    const __bf16* al = xl + (size_t)mb*128*DIM;

    const int lane = tid & 63, wv = tid >> 6;
    const int wm = wv & 1, wn = wv >> 1;          // waves: 2 row-halves x 2 col-halves
    const int quad = lane >> 4, l15 = lane & 15;

    f32x4 acc[4][4][2];
#pragma unroll
    for(int g=0;g<4;g++)
#pragma unroll
        for(int i=0;i<4;i++)
#pragma unroll
            for(int j=0;j<2;j++) acc[g][i][j] = (f32x4){0.f,0.f,0.f,0.f};

    // staging source mapping (undoes the XOR swizzle): thread t -> region row r=t>>2,
    // LDS slot t&3, global seg = (t&3) ^ ((r>>1)&3) = (t&3) ^ ((t>>3)&3)
    const int rA   = tid >> 2;
    const int sseg = ((tid & 3) ^ ((tid >> 3) & 3)) * 8;   // element offset
    char* lds_base = (char*)smem;

    const __bf16* src0 = ah + (size_t)(rA     )*DIM + sseg;
    const __bf16* src1 = ah + (size_t)(64 + rA)*DIM + sseg;
    const __bf16* src2 = al + (size_t)(rA     )*DIM + sseg;
    const __bf16* src3 = al + (size_t)(64 + rA)*DIM + sseg;
    const __bf16* src4 = WT + (size_t)0*DIM*DIM + (size_t)(nb*64 + rA)*DIM + sseg;
    const __bf16* src5 = WT + (size_t)1*DIM*DIM + (size_t)(nb*64 + rA)*DIM + sseg;
    const __bf16* src6 = WT + (size_t)2*DIM*DIM + (size_t)(nb*64 + rA)*DIM + sseg;
    const __bf16* src7 = WT + (size_t)3*DIM*DIM + (size_t)(nb*64 + rA)*DIM + sseg;

#define GLDS(p, dst) __builtin_amdgcn_global_load_lds( \
        (const __attribute__((address_space(1))) void*)(p), \
        (__attribute__((address_space(3))) void*)(dst), 16, 0, 0)

#define STAGE(BUF, K0) do{ \
        char* _db = lds_base + (BUF)*32768; \
        GLDS(src0 + (K0), _db + (0*256+tid)*16); \
        GLDS(src1 + (K0), _db + (1*256+tid)*16); \
        GLDS(src2 + (K0), _db + (2*256+tid)*16); \
        GLDS(src3 + (K0), _db + (3*256+tid)*16); \
        GLDS(src4 + (K0), _db + (4*256+tid)*16); \
        GLDS(src5 + (K0), _db + (5*256+tid)*16); \
        GLDS(src6 + (K0), _db + (6*256+tid)*16); \
        GLDS(src7 + (K0), _db + (7*256+tid)*16); \
    }while(0)

    // fragment read offsets (bytes), swizzle-corrected; constant across i/j since
    // ((base + 16*i)>>1)&3 == (base>>1)&3
    const int rowA  = wm*64 + l15;
    const int offA  = (quad ^ ((rowA>>1)&3))*16;
    const int rowB  = wn*32 + l15;
    const int offB  = (quad ^ ((rowB>>1)&3))*16;

    STAGE(0, 0);

#pragma unroll 2
    for(int kt=0; kt<DIM/32; ++kt){
        char* cb = lds_base + (kt&1)*32768;        // compute buffer
        if(kt < DIM/32 - 1){
            STAGE((kt+1)&1, (kt+1)*32);            // prefetch next tile (overlaps MFMA)
            asm volatile("s_waitcnt vmcnt(8)" ::: "memory");   // retire STAGE(kt); kt+1 stays in flight
        } else {
            asm volatile("s_waitcnt vmcnt(0)" ::: "memory");   // final tile: drain own STAGE
        }
        __builtin_amdgcn_s_barrier();              // B: all waves' STAGE(kt) visible
        asm volatile("" ::: "memory");

        bf16x8 fh[4], fl[4];
#pragma unroll
        for(int i=0;i<4;i++){
            int rbyte = (rowA + i*16)*64 + offA;
            fh[i] = *(const bf16x8*)(cb + rbyte);
            fl[i] = *(const bf16x8*)(cb + 8192 + rbyte);
        }
#pragma unroll
        for(int g=0;g<4;g++){
            bf16x8 fb0 = *(const bf16x8*)(cb + 16384 + g*4096 + (rowB     )*64 + offB);
            bf16x8 fb1 = *(const bf16x8*)(cb + 16384 + g*4096 + (rowB + 16)*64 + offB);
#pragma unroll
            for(int i=0;i<4;i++){
                acc[g][i][0] = __builtin_amdgcn_mfma_f32_16x16x32_bf16(fh[i], fb0, acc[g][i][0], 0,0,0);
                acc[g][i][0] = __builtin_amdgcn_mfma_f32_16x16x32_bf16(fl[i], fb0, acc[g][i][0], 0,0,0);
                acc[g][i][1] = __builtin_amdgcn_mfma_f32_16x16x32_bf16(fh[i], fb1, acc[g][i][1], 0,0,0);
                acc[g][i][1] = __builtin_amdgcn_mfma_f32_16x16x32_bf16(fl[i], fb1, acc[g][i][1], 0,0,0);
            }
        }
        asm volatile("" ::: "memory");
        __builtin_amdgcn_s_barrier();              // A: reads retired -> next STAGE may overwrite
        asm volatile("" ::: "memory");
    }
#undef STAGE
#undef GLDS

    // epilogue: f=sig, inp=tanh*sig, og=sig; bf16 stores
#pragma unroll
    for(int j=0;j<2;j++){
        int col = nb*64 + wn*32 + j*16 + l15;
        float bvf = b0[col], bvi = b1[col], bvg = b2[col], bvo = b3[col];
#pragma unroll
        for(int i=0;i<4;i++){
#pragma unroll
            for(int r=0;r<4;r++){
                int m = mb*128 + wm*64 + i*16 + quad*4 + r;
                size_t o = (size_t)m*DIM + col;
                F[o]   = (__bf16)sigmoid_f(acc[0][i][j][r] + bvf);
                float it = tanh_f   (acc[1][i][j][r] + bvi);
                float ig = sigmoid_f(acc[2][i][j][r] + bvg);
                INP[o] = (__bf16)(it*ig);
                G[o]   = (__bf16)sigmoid_f(acc[3][i][j][r] + bvo);
            }
        }
    }
}

// ---------------- scan pass 1: per-chunk (P = prod f, H = local scan from 0) ----------------
__global__ __launch_bounds__(256) void k_scan1(const __bf16* __restrict__ F, const __bf16* __restrict__ INP,
                                               float* __restrict__ P, float* __restrict__ Hc){
    int c = blockIdx.x, dblk = blockIdx.y, b = blockIdx.z;
    int d = (dblk*256 + threadIdx.x)*2;
    size_t base = ((size_t)(b*LSEQ + c*CLEN))*DIM + d;
    float p0=1.f,p1=1.f,h0=0.f,h1=0.f;
#pragma unroll 4
    for(int t=0;t<CLEN;t++){
        bf16x2 fv = *(const bf16x2*)(F   + base + (size_t)t*DIM);
        bf16x2 iv = *(const bf16x2*)(INP + base + (size_t)t*DIM);
        h0 = (float)fv[0]*h0 + (float)iv[0];
        h1 = (float)fv[1]*h1 + (float)iv[1];
        p0 *= (float)fv[0];
        p1 *= (float)fv[1];
    }
    int bd = b*DIM + d;
    *(float2*)(P  + c*(BSZ*DIM) + bd) = make_float2(p0,p1);
    *(float2*)(Hc + c*(BSZ*DIM) + bd) = make_float2(h0,h1);
}

// ---------------- scan pass 2: chunk-level scan, seeded with last_hidden_init ----------------
__global__ __launch_bounds__(256) void k_scan2(const float* __restrict__ P, const float* __restrict__ Hc,
                                               const float* __restrict__ lh, float* __restrict__ Hin){
    int bd = blockIdx.x*256 + threadIdx.x;   // 0..4095
    int d = bd & (DIM-1);
    float h = lh[d];
#pragma unroll
    for(int c=0;c<CHUNKS;c++){
        Hin[c*(BSZ*DIM) + bd] = h;
        h = P[c*(BSZ*DIM) + bd]*h + Hc[c*(BSZ*DIM) + bd];
    }
}

// ---------------- scan pass 3: replay chunks, fuse y = tanh(h)*G ----------------
__global__ __launch_bounds__(256) void k_scan3(const __bf16* __restrict__ F, const __bf16* __restrict__ INP,
                                               const __bf16* __restrict__ G, const float* __restrict__ Hin,
                                               float* __restrict__ Y){
    int c = blockIdx.x, dblk = blockIdx.y, b = blockIdx.z;
    int d = (dblk*256 + threadIdx.x)*2;
    int bd = b*DIM + d;
    size_t base = ((size_t)(b*LSEQ + c*CLEN))*DIM + d;
    float2 hv = *(const float2*)(Hin + c*(BSZ*DIM) + bd);
    float h0 = hv.x, h1 = hv.y;
#pragma unroll 4
    for(int t=0;t<CLEN;t++){
        size_t o = base + (size_t)t*DIM;
        bf16x2 fv = *(const bf16x2*)(F + o);
        bf16x2 iv = *(const bf16x2*)(INP + o);
        bf16x2 gv = *(const bf16x2*)(G + o);
        h0 = (float)fv[0]*h0 + (float)iv[0];
        h1 = (float)fv[1]*h1 + (float)iv[1];
        *(float2*)(Y + o) = make_float2(tanh_f(h0)*(float)gv[0], tanh_f(h1)*(float)gv[1]);
    }
}

extern "C" void kernel_launch(void* const* d_in, const int* in_sizes, int n_in,
                              void* d_out, int out_size, void* d_ws, size_t ws_size,
                              hipStream_t stream){
    const float* x  = (const float*)d_in[0];
    const float* W[4]    = {(const float*)d_in[1], (const float*)d_in[3],
                            (const float*)d_in[5], (const float*)d_in[7]};
    const float* bias[4] = {(const float*)d_in[2], (const float*)d_in[4],
                            (const float*)d_in[6], (const float*)d_in[8]};
    const float* lh = (const float*)d_in[9];
    float* Y = (float*)d_out;

    char* ws = (char*)d_ws;
    __bf16* xh = (__bf16*)(ws);                         //  64 MiB
    __bf16* xl = (__bf16*)(ws + ((size_t) 64<<20));     //  64 MiB
    __bf16* WT = (__bf16*)(ws + ((size_t)128<<20));     //   8 MiB
    __bf16* F  = (__bf16*)(ws + ((size_t)136<<20));     //  64 MiB
    __bf16* INP= (__bf16*)(ws + ((size_t)200<<20));     //  64 MiB
    __bf16* G  = (__bf16*)(ws + ((size_t)264<<20));     //  64 MiB
    float*  P  = (float*) (ws + ((size_t)328<<20));     //   1 MiB
    float*  Hc = (float*) (ws + ((size_t)329<<20));     //   1 MiB
    float*  Hin= (float*) (ws + ((size_t)330<<20));     //   1 MiB  (total 331 MiB)

    hipLaunchKernelGGL(k_convert_x, dim3(M_TOT*DIM/(4*256)), dim3(256), 0, stream, x, xh, xl);
    hipLaunchKernelGGL(k_convert_w, dim3(32,32,4), dim3(32,8), 0, stream,
                       W[0], W[1], W[2], W[3], WT);
    hipLaunchKernelGGL(k_gemm, dim3(16, M_TOT/128), dim3(256), 0, stream,
                       xh, xl, WT, bias[0], bias[1], bias[2], bias[3], F, INP, G);
    hipLaunchKernelGGL(k_scan1, dim3(CHUNKS, DIM/512, BSZ), dim3(256), 0, stream, F, INP, P, Hc);
    hipLaunchKernelGGL(k_scan2, dim3(BSZ*DIM/256), dim3(256), 0, stream, P, Hc, lh, Hin);
    hipLaunchKernelGGL(k_scan3, dim3(CHUNKS, DIM/512, BSZ), dim3(256), 0, stream, F, INP, G, Hin, Y);
}

// Round 6
// 702.515 us; speedup vs baseline: 1.2870x; 1.1566x over previous
//
#include <hip/hip_runtime.h>
#include <hip/hip_bf16.h>
#include <hip/hip_fp16.h>

typedef __bf16    bf16x4 __attribute__((ext_vector_type(4)));
typedef __bf16    bf16x2 __attribute__((ext_vector_type(2)));
typedef _Float16  f16x8  __attribute__((ext_vector_type(8)));
typedef _Float16  f16x4  __attribute__((ext_vector_type(4)));
typedef float     f32x4  __attribute__((ext_vector_type(4)));

#define DIM   1024
#define BSZ   4
#define LSEQ  8192
#define M_TOT (BSZ*LSEQ)      /* 32768 rows */
#define CHUNKS 64
#define CLEN  (LSEQ/CHUNKS)   /* 128 */

__device__ __forceinline__ float sigmoid_f(float z){ return 1.0f/(1.0f + __expf(-z)); }
__device__ __forceinline__ float tanh_f(float z){ return 1.0f - 2.0f/(__expf(2.0f*z) + 1.0f); }

// ---------------- prepass: x (fp32) -> xf (fp16) ----------------
// fp16 (2^-11 rel) replaces the bf16 hi/lo split: W was bf16 (2^-9) anyway, so
// fp16-for-both LOWERS pre-activation error while halving MFMA work.
__global__ __launch_bounds__(256) void k_convert_x(const float* __restrict__ x,
                                                   _Float16* __restrict__ xf){
    int i = (blockIdx.x*256 + threadIdx.x)*4;
    float4 v = *(const float4*)(x + i);
    f16x4 h = { (_Float16)v.x, (_Float16)v.y, (_Float16)v.z, (_Float16)v.w };
    *(f16x4*)(xf + i) = h;
}

// ---------------- prepass: W (fp32, [k][n]) -> WT (fp16, [n][k]), 4 gates ----------------
__global__ __launch_bounds__(256) void k_convert_w(const float* __restrict__ W0,
                                                   const float* __restrict__ W1,
                                                   const float* __restrict__ W2,
                                                   const float* __restrict__ W3,
                                                   _Float16* __restrict__ WT){
    __shared__ float t[32][33];
    int tx = threadIdx.x, ty = threadIdx.y;          // block (32,8)
    int n0 = blockIdx.x*32, k0 = blockIdx.y*32;
    int g = blockIdx.z;
    const float* W = (g==0)?W0:(g==1)?W1:(g==2)?W2:W3;
    _Float16* wt = WT + (size_t)g*DIM*DIM;
#pragma unroll
    for(int j=0;j<4;j++)
        t[ty + j*8][tx] = W[(size_t)(k0 + ty + j*8)*DIM + n0 + tx];
    __syncthreads();
#pragma unroll
    for(int j=0;j<4;j++)
        wt[(size_t)(n0 + ty + j*8)*DIM + k0 + tx] = (_Float16)t[tx][ty + j*8];
}

// ---------------- unified 4-gate GEMM, fp16 single-precision ----------------
// Block computes 128(M) x 64(N) for ALL 4 gates. R1-measured-best schedule
// (single __syncthreads per K-step, 2-buffer prefetch), now fp16 => half the
// MFMA work, 2/3 the LDS traffic, and 48 KiB LDS -> 3 blocks/CU (12 waves).
// LDS buffer (24 KiB, 6 regions x 4 KiB): [0,1]=A rows 0-63/64-127, [2..5]=B gate 0..3.
// Rows are 64 B (32 fp16) exactly as before -> R1-verified XOR swizzle carries over:
// element (row r, 16B k-seg q) lives at r*64 + (q ^ ((r>>1)&3))*16; 0 bank conflicts.
__global__ __launch_bounds__(256,3) void k_gemm(
        const _Float16* __restrict__ xf,
        const _Float16* __restrict__ WT,          // [4][DIM][DIM], n-major
        const float* __restrict__ b0, const float* __restrict__ b1,
        const float* __restrict__ b2, const float* __restrict__ b3,
        __bf16* __restrict__ F, __bf16* __restrict__ INP, __bf16* __restrict__ G)
{
    __shared__ _Float16 smem[2*6*2048];   // 48 KiB (2 buffers x 24 KiB)
    const int tid = threadIdx.x;
    const int nb = blockIdx.x, mb = blockIdx.y;

    const _Float16* ax = xf + (size_t)mb*128*DIM;

    const int lane = tid & 63, wv = tid >> 6;
    const int wm = wv & 1, wn = wv >> 1;          // waves: 2 row-halves x 2 col-halves
    const int quad = lane >> 4, l15 = lane & 15;

    f32x4 acc[4][4][2];
#pragma unroll
    for(int g=0;g<4;g++)
#pragma unroll
        for(int i=0;i<4;i++)
#pragma unroll
            for(int j=0;j<2;j++) acc[g][i][j] = (f32x4){0.f,0.f,0.f,0.f};

    // staging source mapping (undoes the XOR swizzle): thread t -> region row r=t>>2,
    // LDS slot t&3, global seg = (t&3) ^ ((r>>1)&3) = (t&3) ^ ((t>>3)&3)
    const int rA   = tid >> 2;
    const int sseg = ((tid & 3) ^ ((tid >> 3) & 3)) * 8;   // element offset (8 fp16 = 16 B)
    char* lds_base = (char*)smem;

    const _Float16* src0 = ax + (size_t)(rA     )*DIM + sseg;
    const _Float16* src1 = ax + (size_t)(64 + rA)*DIM + sseg;
    const _Float16* src2 = WT + (size_t)0*DIM*DIM + (size_t)(nb*64 + rA)*DIM + sseg;
    const _Float16* src3 = WT + (size_t)1*DIM*DIM + (size_t)(nb*64 + rA)*DIM + sseg;
    const _Float16* src4 = WT + (size_t)2*DIM*DIM + (size_t)(nb*64 + rA)*DIM + sseg;
    const _Float16* src5 = WT + (size_t)3*DIM*DIM + (size_t)(nb*64 + rA)*DIM + sseg;

#define GLDS(p, dst) __builtin_amdgcn_global_load_lds( \
        (const __attribute__((address_space(1))) void*)(p), \
        (__attribute__((address_space(3))) void*)(dst), 16, 0, 0)

#define STAGE(BUF, K0) do{ \
        char* _db = lds_base + (BUF)*24576; \
        GLDS(src0 + (K0), _db + (0*256+tid)*16); \
        GLDS(src1 + (K0), _db + (1*256+tid)*16); \
        GLDS(src2 + (K0), _db + (2*256+tid)*16); \
        GLDS(src3 + (K0), _db + (3*256+tid)*16); \
        GLDS(src4 + (K0), _db + (4*256+tid)*16); \
        GLDS(src5 + (K0), _db + (5*256+tid)*16); \
    }while(0)

    // fragment read offsets (bytes), swizzle-corrected; constant across i/j since
    // ((base + 16*i)>>1)&3 == (base>>1)&3
    const int rowA  = wm*64 + l15;
    const int offA  = (quad ^ ((rowA>>1)&3))*16;
    const int rowB  = wn*32 + l15;
    const int offB  = (quad ^ ((rowB>>1)&3))*16;

    STAGE(0, 0);
    __syncthreads();                 // buffer 0 ready

#pragma unroll 2
    for(int kt=0; kt<DIM/32; ++kt){
        char* cb = lds_base + (kt&1)*24576;        // compute buffer
        if(kt < DIM/32 - 1)
            STAGE((kt+1)&1, (kt+1)*32);            // prefetch next tile (overlaps MFMA)

        f16x8 fa[4];
#pragma unroll
        for(int i=0;i<4;i++)
            fa[i] = *(const f16x8*)(cb + (rowA + i*16)*64 + offA);
#pragma unroll
        for(int g=0;g<4;g++){
            f16x8 fb0 = *(const f16x8*)(cb + 8192 + g*4096 + (rowB     )*64 + offB);
            f16x8 fb1 = *(const f16x8*)(cb + 8192 + g*4096 + (rowB + 16)*64 + offB);
#pragma unroll
            for(int i=0;i<4;i++){
                acc[g][i][0] = __builtin_amdgcn_mfma_f32_16x16x32_f16(fa[i], fb0, acc[g][i][0], 0,0,0);
                acc[g][i][1] = __builtin_amdgcn_mfma_f32_16x16x32_f16(fa[i], fb1, acc[g][i][1], 0,0,0);
            }
        }
        __syncthreads();             // drains prefetch + read-retire (R1-measured-best)
    }
#undef STAGE
#undef GLDS

    // epilogue: f=sig, inp=tanh*sig, og=sig; bf16 stores
#pragma unroll
    for(int j=0;j<2;j++){
        int col = nb*64 + wn*32 + j*16 + l15;
        float bvf = b0[col], bvi = b1[col], bvg = b2[col], bvo = b3[col];
#pragma unroll
        for(int i=0;i<4;i++){
#pragma unroll
            for(int r=0;r<4;r++){
                int m = mb*128 + wm*64 + i*16 + quad*4 + r;
                size_t o = (size_t)m*DIM + col;
                F[o]   = (__bf16)sigmoid_f(acc[0][i][j][r] + bvf);
                float it = tanh_f   (acc[1][i][j][r] + bvi);
                float ig = sigmoid_f(acc[2][i][j][r] + bvg);
                INP[o] = (__bf16)(it*ig);
                G[o]   = (__bf16)sigmoid_f(acc[3][i][j][r] + bvo);
            }
        }
    }
}

// ---------------- scan pass 1: per-chunk (P = prod f, H = local scan from 0) ----------------
__global__ __launch_bounds__(256) void k_scan1(const __bf16* __restrict__ F, const __bf16* __restrict__ INP,
                                               float* __restrict__ P, float* __restrict__ Hc){
    int c = blockIdx.x, dblk = blockIdx.y, b = blockIdx.z;
    int d = (dblk*256 + threadIdx.x)*2;
    size_t base = ((size_t)(b*LSEQ + c*CLEN))*DIM + d;
    float p0=1.f,p1=1.f,h0=0.f,h1=0.f;
#pragma unroll 4
    for(int t=0;t<CLEN;t++){
        bf16x2 fv = *(const bf16x2*)(F   + base + (size_t)t*DIM);
        bf16x2 iv = *(const bf16x2*)(INP + base + (size_t)t*DIM);
        h0 = (float)fv[0]*h0 + (float)iv[0];
        h1 = (float)fv[1]*h1 + (float)iv[1];
        p0 *= (float)fv[0];
        p1 *= (float)fv[1];
    }
    int bd = b*DIM + d;
    *(float2*)(P  + c*(BSZ*DIM) + bd) = make_float2(p0,p1);
    *(float2*)(Hc + c*(BSZ*DIM) + bd) = make_float2(h0,h1);
}

// ---------------- scan pass 2: chunk-level scan, seeded with last_hidden_init ----------------
__global__ __launch_bounds__(256) void k_scan2(const float* __restrict__ P, const float* __restrict__ Hc,
                                               const float* __restrict__ lh, float* __restrict__ Hin){
    int bd = blockIdx.x*256 + threadIdx.x;   // 0..4095
    int d = bd & (DIM-1);
    float h = lh[d];
#pragma unroll
    for(int c=0;c<CHUNKS;c++){
        Hin[c*(BSZ*DIM) + bd] = h;
        h = P[c*(BSZ*DIM) + bd]*h + Hc[c*(BSZ*DIM) + bd];
    }
}

// ---------------- scan pass 3: replay chunks, fuse y = tanh(h)*G ----------------
__global__ __launch_bounds__(256) void k_scan3(const __bf16* __restrict__ F, const __bf16* __restrict__ INP,
                                               const __bf16* __restrict__ G, const float* __restrict__ Hin,
                                               float* __restrict__ Y){
    int c = blockIdx.x, dblk = blockIdx.y, b = blockIdx.z;
    int d = (dblk*256 + threadIdx.x)*2;
    int bd = b*DIM + d;
    size_t base = ((size_t)(b*LSEQ + c*CLEN))*DIM + d;
    float2 hv = *(const float2*)(Hin + c*(BSZ*DIM) + bd);
    float h0 = hv.x, h1 = hv.y;
#pragma unroll 4
    for(int t=0;t<CLEN;t++){
        size_t o = base + (size_t)t*DIM;
        bf16x2 fv = *(const bf16x2*)(F + o);
        bf16x2 iv = *(const bf16x2*)(INP + o);
        bf16x2 gv = *(const bf16x2*)(G + o);
        h0 = (float)fv[0]*h0 + (float)iv[0];
        h1 = (float)fv[1]*h1 + (float)iv[1];
        *(float2*)(Y + o) = make_float2(tanh_f(h0)*(float)gv[0], tanh_f(h1)*(float)gv[1]);
    }
}

extern "C" void kernel_launch(void* const* d_in, const int* in_sizes, int n_in,
                              void* d_out, int out_size, void* d_ws, size_t ws_size,
                              hipStream_t stream){
    const float* x  = (const float*)d_in[0];
    const float* W[4]    = {(const float*)d_in[1], (const float*)d_in[3],
                            (const float*)d_in[5], (const float*)d_in[7]};
    const float* bias[4] = {(const float*)d_in[2], (const float*)d_in[4],
                            (const float*)d_in[6], (const float*)d_in[8]};
    const float* lh = (const float*)d_in[9];
    float* Y = (float*)d_out;

    char* ws = (char*)d_ws;
    _Float16* xf = (_Float16*)(ws);                     //  64 MiB
    _Float16* WT = (_Float16*)(ws + ((size_t) 64<<20)); //   8 MiB
    __bf16* F  = (__bf16*)(ws + ((size_t) 72<<20));     //  64 MiB
    __bf16* INP= (__bf16*)(ws + ((size_t)136<<20));     //  64 MiB
    __bf16* G  = (__bf16*)(ws + ((size_t)200<<20));     //  64 MiB
    float*  P  = (float*) (ws + ((size_t)264<<20));     //   1 MiB
    float*  Hc = (float*) (ws + ((size_t)265<<20));     //   1 MiB
    float*  Hin= (float*) (ws + ((size_t)266<<20));     //   1 MiB  (total 267 MiB)

    hipLaunchKernelGGL(k_convert_x, dim3(M_TOT*DIM/(4*256)), dim3(256), 0, stream, x, xf);
    hipLaunchKernelGGL(k_convert_w, dim3(32,32,4), dim3(32,8), 0, stream,
                       W[0], W[1], W[2], W[3], WT);
    hipLaunchKernelGGL(k_gemm, dim3(16, M_TOT/128), dim3(256), 0, stream,
                       xf, WT, bias[0], bias[1], bias[2], bias[3], F, INP, G);
    hipLaunchKernelGGL(k_scan1, dim3(CHUNKS, DIM/512, BSZ), dim3(256), 0, stream, F, INP, P, Hc);
    hipLaunchKernelGGL(k_scan2, dim3(BSZ*DIM/256), dim3(256), 0, stream, P, Hc, lh, Hin);
    hipLaunchKernelGGL(k_scan3, dim3(CHUNKS, DIM/512, BSZ), dim3(256), 0, stream, F, INP, G, Hin, Y);
}

// Round 7
// 648.767 us; speedup vs baseline: 1.3936x; 1.0828x over previous
//
#include <hip/hip_runtime.h>
#include <hip/hip_bf16.h>
#include <hip/hip_fp16.h>

typedef __bf16    bf16x8 __attribute__((ext_vector_type(8)));
typedef __bf16    bf16x4 __attribute__((ext_vector_type(4)));
typedef __bf16    bf16x2 __attribute__((ext_vector_type(2)));
typedef _Float16  f16x8  __attribute__((ext_vector_type(8)));
typedef _Float16  f16x4  __attribute__((ext_vector_type(4)));
typedef float     f32x4  __attribute__((ext_vector_type(4)));

#define DIM   1024
#define BSZ   4
#define LSEQ  8192
#define M_TOT (BSZ*LSEQ)      /* 32768 rows */
#define CHUNKS 64
#define CLEN  (LSEQ/CHUNKS)   /* 128 */

__device__ __forceinline__ float sigmoid_f(float z){ return 1.0f/(1.0f + __expf(-z)); }
__device__ __forceinline__ float tanh_f(float z){ return 1.0f - 2.0f/(__expf(2.0f*z) + 1.0f); }

// ---------------- prepass: x (fp32) -> xf (fp16) ----------------
__global__ __launch_bounds__(256) void k_convert_x(const float* __restrict__ x,
                                                   _Float16* __restrict__ xf){
    int i = (blockIdx.x*256 + threadIdx.x)*4;
    float4 v = *(const float4*)(x + i);
    f16x4 h = { (_Float16)v.x, (_Float16)v.y, (_Float16)v.z, (_Float16)v.w };
    *(f16x4*)(xf + i) = h;
}

// ---------------- prepass: W (fp32, [k][n]) -> WT (fp16, [n][k]), 4 gates ----------------
__global__ __launch_bounds__(256) void k_convert_w(const float* __restrict__ W0,
                                                   const float* __restrict__ W1,
                                                   const float* __restrict__ W2,
                                                   const float* __restrict__ W3,
                                                   _Float16* __restrict__ WT){
    __shared__ float t[32][33];
    int tx = threadIdx.x, ty = threadIdx.y;          // block (32,8)
    int n0 = blockIdx.x*32, k0 = blockIdx.y*32;
    int g = blockIdx.z;
    const float* W = (g==0)?W0:(g==1)?W1:(g==2)?W2:W3;
    _Float16* wt = WT + (size_t)g*DIM*DIM;
#pragma unroll
    for(int j=0;j<4;j++)
        t[ty + j*8][tx] = W[(size_t)(k0 + ty + j*8)*DIM + n0 + tx];
    __syncthreads();
#pragma unroll
    for(int j=0;j<4;j++)
        wt[(size_t)(n0 + ty + j*8)*DIM + k0 + tx] = (_Float16)t[tx][ty + j*8];
}

// ---------------- unified 4-gate GEMM, fp16, LDS-coalesced epilogue ----------------
// Block computes 128(M) x 64(N) for ALL 4 gates. R6 schedule unchanged (measured best:
// single __syncthreads per K-step, 2-buffer prefetch, 48 KiB LDS -> 3 blocks/CU).
// LDS buffer (24 KiB, 6 regions x 4 KiB): [0,1]=A rows 0-63/64-127, [2..5]=B gate 0..3.
// XOR swizzle (verified 0-conflict): elem (row r, 16B k-seg q) at r*64 + (q ^ ((r>>1)&3))*16.
// NEW (R7): epilogue stages the 3 output tiles through the (now-dead) 48 KiB smem and
// stores with full-line global_store_dwordx4 — removes the 2B-scattered partial-line
// writes that caused WRITE_SIZE 486 MB / FETCH 348 MB (RMW amplification) in R6.
__global__ __launch_bounds__(256,3) void k_gemm(
        const _Float16* __restrict__ xf,
        const _Float16* __restrict__ WT,          // [4][DIM][DIM], n-major
        const float* __restrict__ b0, const float* __restrict__ b1,
        const float* __restrict__ b2, const float* __restrict__ b3,
        __bf16* __restrict__ F, __bf16* __restrict__ INP, __bf16* __restrict__ G)
{
    __shared__ _Float16 smem[2*6*2048];   // 48 KiB (2 buffers x 24 KiB)
    const int tid = threadIdx.x;
    const int nb = blockIdx.x, mb = blockIdx.y;

    const _Float16* ax = xf + (size_t)mb*128*DIM;

    const int lane = tid & 63, wv = tid >> 6;
    const int wm = wv & 1, wn = wv >> 1;          // waves: 2 row-halves x 2 col-halves
    const int quad = lane >> 4, l15 = lane & 15;

    f32x4 acc[4][4][2];
#pragma unroll
    for(int g=0;g<4;g++)
#pragma unroll
        for(int i=0;i<4;i++)
#pragma unroll
            for(int j=0;j<2;j++) acc[g][i][j] = (f32x4){0.f,0.f,0.f,0.f};

    // staging source mapping (undoes the XOR swizzle): thread t -> region row r=t>>2,
    // LDS slot t&3, global seg = (t&3) ^ ((r>>1)&3) = (t&3) ^ ((t>>3)&3)
    const int rA   = tid >> 2;
    const int sseg = ((tid & 3) ^ ((tid >> 3) & 3)) * 8;   // element offset (8 fp16 = 16 B)
    char* lds_base = (char*)smem;

    const _Float16* src0 = ax + (size_t)(rA     )*DIM + sseg;
    const _Float16* src1 = ax + (size_t)(64 + rA)*DIM + sseg;
    const _Float16* src2 = WT + (size_t)0*DIM*DIM + (size_t)(nb*64 + rA)*DIM + sseg;
    const _Float16* src3 = WT + (size_t)1*DIM*DIM + (size_t)(nb*64 + rA)*DIM + sseg;
    const _Float16* src4 = WT + (size_t)2*DIM*DIM + (size_t)(nb*64 + rA)*DIM + sseg;
    const _Float16* src5 = WT + (size_t)3*DIM*DIM + (size_t)(nb*64 + rA)*DIM + sseg;

#define GLDS(p, dst) __builtin_amdgcn_global_load_lds( \
        (const __attribute__((address_space(1))) void*)(p), \
        (__attribute__((address_space(3))) void*)(dst), 16, 0, 0)

#define STAGE(BUF, K0) do{ \
        char* _db = lds_base + (BUF)*24576; \
        GLDS(src0 + (K0), _db + (0*256+tid)*16); \
        GLDS(src1 + (K0), _db + (1*256+tid)*16); \
        GLDS(src2 + (K0), _db + (2*256+tid)*16); \
        GLDS(src3 + (K0), _db + (3*256+tid)*16); \
        GLDS(src4 + (K0), _db + (4*256+tid)*16); \
        GLDS(src5 + (K0), _db + (5*256+tid)*16); \
    }while(0)

    // fragment read offsets (bytes), swizzle-corrected; constant across i/j since
    // ((base + 16*i)>>1)&3 == (base>>1)&3
    const int rowA  = wm*64 + l15;
    const int offA  = (quad ^ ((rowA>>1)&3))*16;
    const int rowB  = wn*32 + l15;
    const int offB  = (quad ^ ((rowB>>1)&3))*16;

    STAGE(0, 0);
    __syncthreads();                 // buffer 0 ready

#pragma unroll 2
    for(int kt=0; kt<DIM/32; ++kt){
        char* cb = lds_base + (kt&1)*24576;        // compute buffer
        if(kt < DIM/32 - 1)
            STAGE((kt+1)&1, (kt+1)*32);            // prefetch next tile (overlaps MFMA)

        f16x8 fa[4];
#pragma unroll
        for(int i=0;i<4;i++)
            fa[i] = *(const f16x8*)(cb + (rowA + i*16)*64 + offA);
#pragma unroll
        for(int g=0;g<4;g++){
            f16x8 fb0 = *(const f16x8*)(cb + 8192 + g*4096 + (rowB     )*64 + offB);
            f16x8 fb1 = *(const f16x8*)(cb + 8192 + g*4096 + (rowB + 16)*64 + offB);
#pragma unroll
            for(int i=0;i<4;i++){
                acc[g][i][0] = __builtin_amdgcn_mfma_f32_16x16x32_f16(fa[i], fb0, acc[g][i][0], 0,0,0);
                acc[g][i][1] = __builtin_amdgcn_mfma_f32_16x16x32_f16(fa[i], fb1, acc[g][i][1], 0,0,0);
            }
        }
        __syncthreads();             // drains prefetch + read-retire (measured best)
    }
#undef STAGE
#undef GLDS

    // ---------------- epilogue: activate -> LDS tiles -> coalesced wide stores ----------
    // smem is dead after the loop's final __syncthreads. 3 regions x 16 KiB = 48 KiB:
    // region[a] = [128 rows][64 cols] bf16, row stride 128 B.
    {
        __bf16* eF = (__bf16*)lds_base;              // 16 KiB
        __bf16* eI = (__bf16*)(lds_base + 16384);    // 16 KiB
        __bf16* eG = (__bf16*)(lds_base + 32768);    // 16 KiB
#pragma unroll
        for(int j=0;j<2;j++){
            int colL = wn*32 + j*16 + l15;           // local col 0..63
            int col  = nb*64 + colL;
            float bvf = b0[col], bvi = b1[col], bvg = b2[col], bvo = b3[col];
#pragma unroll
            for(int i=0;i<4;i++){
#pragma unroll
                for(int r=0;r<4;r++){
                    int mL = wm*64 + i*16 + quad*4 + r;      // local row 0..127
                    int o  = mL*64 + colL;
                    eF[o] = (__bf16)sigmoid_f(acc[0][i][j][r] + bvf);
                    float it = tanh_f   (acc[1][i][j][r] + bvi);
                    float ig = sigmoid_f(acc[2][i][j][r] + bvg);
                    eI[o] = (__bf16)(it*ig);
                    eG[o] = (__bf16)sigmoid_f(acc[3][i][j][r] + bvo);
                }
            }
        }
        __syncthreads();
        // read-back: 8 lanes own one 128 B row -> conflict-free b128 reads,
        // full-line dwordx4 global stores. 4 passes of 32 rows each.
        const int rrow = tid >> 3;          // 0..31
        const int coff = (tid & 7) * 8;     // 8 bf16 = 16 B
#pragma unroll
        for(int p=0;p<4;p++){
            int mL = p*32 + rrow;
            size_t go = (size_t)(mb*128 + mL)*DIM + nb*64 + coff;
            int    lo = mL*64 + coff;
            *(bf16x8*)(F   + go) = *(const bf16x8*)(eF + lo);
            *(bf16x8*)(INP + go) = *(const bf16x8*)(eI + lo);
            *(bf16x8*)(G   + go) = *(const bf16x8*)(eG + lo);
        }
    }
}

// ---------------- scan pass 1: per-chunk (P = prod f, H = local scan from 0) ----------------
__global__ __launch_bounds__(256) void k_scan1(const __bf16* __restrict__ F, const __bf16* __restrict__ INP,
                                               float* __restrict__ P, float* __restrict__ Hc){
    int c = blockIdx.x, dblk = blockIdx.y, b = blockIdx.z;
    int d = (dblk*256 + threadIdx.x)*2;
    size_t base = ((size_t)(b*LSEQ + c*CLEN))*DIM + d;
    float p0=1.f,p1=1.f,h0=0.f,h1=0.f;
#pragma unroll 4
    for(int t=0;t<CLEN;t++){
        bf16x2 fv = *(const bf16x2*)(F   + base + (size_t)t*DIM);
        bf16x2 iv = *(const bf16x2*)(INP + base + (size_t)t*DIM);
        h0 = (float)fv[0]*h0 + (float)iv[0];
        h1 = (float)fv[1]*h1 + (float)iv[1];
        p0 *= (float)fv[0];
        p1 *= (float)fv[1];
    }
    int bd = b*DIM + d;
    *(float2*)(P  + c*(BSZ*DIM) + bd) = make_float2(p0,p1);
    *(float2*)(Hc + c*(BSZ*DIM) + bd) = make_float2(h0,h1);
}

// ---------------- scan pass 2: chunk-level scan, seeded with last_hidden_init ----------------
__global__ __launch_bounds__(256) void k_scan2(const float* __restrict__ P, const float* __restrict__ Hc,
                                               const float* __restrict__ lh, float* __restrict__ Hin){
    int bd = blockIdx.x*256 + threadIdx.x;   // 0..4095
    int d = bd & (DIM-1);
    float h = lh[d];
#pragma unroll
    for(int c=0;c<CHUNKS;c++){
        Hin[c*(BSZ*DIM) + bd] = h;
        h = P[c*(BSZ*DIM) + bd]*h + Hc[c*(BSZ*DIM) + bd];
    }
}

// ---------------- scan pass 3: replay chunks, fuse y = tanh(h)*G ----------------
__global__ __launch_bounds__(256) void k_scan3(const __bf16* __restrict__ F, const __bf16* __restrict__ INP,
                                               const __bf16* __restrict__ G, const float* __restrict__ Hin,
                                               float* __restrict__ Y){
    int c = blockIdx.x, dblk = blockIdx.y, b = blockIdx.z;
    int d = (dblk*256 + threadIdx.x)*2;
    int bd = b*DIM + d;
    size_t base = ((size_t)(b*LSEQ + c*CLEN))*DIM + d;
    float2 hv = *(const float2*)(Hin + c*(BSZ*DIM) + bd);
    float h0 = hv.x, h1 = hv.y;
#pragma unroll 4
    for(int t=0;t<CLEN;t++){
        size_t o = base + (size_t)t*DIM;
        bf16x2 fv = *(const bf16x2*)(F + o);
        bf16x2 iv = *(const bf16x2*)(INP + o);
        bf16x2 gv = *(const bf16x2*)(G + o);
        h0 = (float)fv[0]*h0 + (float)iv[0];
        h1 = (float)fv[1]*h1 + (float)iv[1];
        *(float2*)(Y + o) = make_float2(tanh_f(h0)*(float)gv[0], tanh_f(h1)*(float)gv[1]);
    }
}

extern "C" void kernel_launch(void* const* d_in, const int* in_sizes, int n_in,
                              void* d_out, int out_size, void* d_ws, size_t ws_size,
                              hipStream_t stream){
    const float* x  = (const float*)d_in[0];
    const float* W[4]    = {(const float*)d_in[1], (const float*)d_in[3],
                            (const float*)d_in[5], (const float*)d_in[7]};
    const float* bias[4] = {(const float*)d_in[2], (const float*)d_in[4],
                            (const float*)d_in[6], (const float*)d_in[8]};
    const float* lh = (const float*)d_in[9];
    float* Y = (float*)d_out;

    char* ws = (char*)d_ws;
    _Float16* xf = (_Float16*)(ws);                     //  64 MiB
    _Float16* WT = (_Float16*)(ws + ((size_t) 64<<20)); //   8 MiB
    __bf16* F  = (__bf16*)(ws + ((size_t) 72<<20));     //  64 MiB
    __bf16* INP= (__bf16*)(ws + ((size_t)136<<20));     //  64 MiB
    __bf16* G  = (__bf16*)(ws + ((size_t)200<<20));     //  64 MiB
    float*  P  = (float*) (ws + ((size_t)264<<20));     //   1 MiB
    float*  Hc = (float*) (ws + ((size_t)265<<20));     //   1 MiB
    float*  Hin= (float*) (ws + ((size_t)266<<20));     //   1 MiB  (total 267 MiB)

    hipLaunchKernelGGL(k_convert_x, dim3(M_TOT*DIM/(4*256)), dim3(256), 0, stream, x, xf);
    hipLaunchKernelGGL(k_convert_w, dim3(32,32,4), dim3(32,8), 0, stream,
                       W[0], W[1], W[2], W[3], WT);
    hipLaunchKernelGGL(k_gemm, dim3(16, M_TOT/128), dim3(256), 0, stream,
                       xf, WT, bias[0], bias[1], bias[2], bias[3], F, INP, G);
    hipLaunchKernelGGL(k_scan1, dim3(CHUNKS, DIM/512, BSZ), dim3(256), 0, stream, F, INP, P, Hc);
    hipLaunchKernelGGL(k_scan2, dim3(BSZ*DIM/256), dim3(256), 0, stream, P, Hc, lh, Hin);
    hipLaunchKernelGGL(k_scan3, dim3(CHUNKS, DIM/512, BSZ), dim3(256), 0, stream, F, INP, G, Hin, Y);
}